// Round 13
// baseline (242.165 us; speedup 1.0000x reference)
//
#include <hip/hip_runtime.h>

// GraphSAGE (2x SAGEConv mean + global_mean_pool + linear) collapsed algebraically:
// out = (((St@W1l + Sw@W1r + Wsum*b1) @ W2l + (Sw@W1l + Sx@W1r + N*b1) @ W2r)/N + b2) @ Wout + bout
// invc_i = 1/max(indeg_i,1), ws_j = sum_{e:src=j} invc[dst_e], u_j = ws_j*invc_j,
// t_k = sum_{e:src=k} u[dst_e]; Sx/Sw/St = weighted column sums of x; Wsum = sum ws.
//
// R12: scat/cnt ILP. Gathers val[d] hoisted out of the src-range predicate
// (always-safe index) and 2 int4-pairs per loop iteration -> 8 independent
// gathers in flight per thread. Everything else = R11 (best, 187 us).
// Invariants: no global atomics (memory-side regardless of scope: R2/R4),
// no grid.sync (~30 us/barrier: R7), LDS range privatization, 7 dispatches.

#define NN    100000
#define NE    1600000
#define NE4   (NE/4)
#define FEAT  128
#define NCLS  40

// count pass (u8-packed)
#define RSC   25000    // nodes per range; 4 cnt/u32 -> 25,000 B LDS
#define NRC   4        // 4*25000 = 100000 exactly
#define NCC   64
#define PERC  6250     // int4 per chunk (64*6250 = 400000)

// scatter passes
#define RSV   16000    // 64,000 B LDS
#define NRV   7
#define NCV   32
#define PERV  12500

// fused merge_t + featsums
#define SLICE 200
#define FSG   500      // grid; 500*200 = 100000 exactly
#define P1S   400      // p1 row stride floats, b-major: p1[b*P1S + v]
#define NV    (3*FEAT + 1)   // 385
#define NQ    (P1S / 4)      // 100 float4 columns per row
#define NG    10             // b-groups in k_fin reduce (10*50 = FSG)

// ======================= count: u8-packed LDS histogram =======================

__global__ __launch_bounds__(1024) void k_cnt8(const int4* __restrict__ dst4,
                                               unsigned* __restrict__ pc) {
    __shared__ unsigned tab[RSC / 4];
    const int c = blockIdx.x, r = blockIdx.y;
    for (int j = threadIdx.x; j < RSC / 4; j += 1024) tab[j] = 0u;
    __syncthreads();
    const int base = r * RSC;
    const int i0 = c * PERC;
    // 2 int4 per iteration (PERC/2048 = 3.05 -> 4 strided steps of 2)
    for (int i = i0 + (int)threadIdx.x * 2; i < i0 + PERC; i += 2048) {
        int4 d0 = dst4[i];
        int4 d1 = dst4[i + 1];
        unsigned a;
        a = (unsigned)(d0.x - base); if (a < RSC) atomicAdd(&tab[a >> 2], 1u << ((a & 3) * 8));
        a = (unsigned)(d0.y - base); if (a < RSC) atomicAdd(&tab[a >> 2], 1u << ((a & 3) * 8));
        a = (unsigned)(d0.z - base); if (a < RSC) atomicAdd(&tab[a >> 2], 1u << ((a & 3) * 8));
        a = (unsigned)(d0.w - base); if (a < RSC) atomicAdd(&tab[a >> 2], 1u << ((a & 3) * 8));
        a = (unsigned)(d1.x - base); if (a < RSC) atomicAdd(&tab[a >> 2], 1u << ((a & 3) * 8));
        a = (unsigned)(d1.y - base); if (a < RSC) atomicAdd(&tab[a >> 2], 1u << ((a & 3) * 8));
        a = (unsigned)(d1.z - base); if (a < RSC) atomicAdd(&tab[a >> 2], 1u << ((a & 3) * 8));
        a = (unsigned)(d1.w - base); if (a < RSC) atomicAdd(&tab[a >> 2], 1u << ((a & 3) * 8));
    }
    __syncthreads();
    unsigned* outp = pc + (size_t)(r * NCC + c) * (RSC / 4);
    for (int j = threadIdx.x; j < RSC / 4; j += 1024) outp[j] = tab[j];
}

__global__ __launch_bounds__(256) void k_inv(const unsigned* __restrict__ pc,
                                             float* __restrict__ invc) {
    int i = blockIdx.x * 256 + threadIdx.x;
    if (i >= NN) return;
    int rr = i / RSC, jj = i - rr * RSC;
    const unsigned* p = pc + (size_t)rr * NCC * (RSC / 4) + (jj >> 2);
    const unsigned sh = (unsigned)(jj & 3) * 8u;
    unsigned cn = 0;
    #pragma unroll 16
    for (int c = 0; c < NCC; ++c) cn += (p[(size_t)c * (RSC / 4)] >> sh) & 0xFFu;
    invc[i] = 1.0f / (float)(cn > 0u ? cn : 1u);
}

// ======================= scatter: 64 KB LDS tables, hoisted gathers =======================

__global__ __launch_bounds__(1024) void k_scat(const int4* __restrict__ src4,
                                               const int4* __restrict__ dst4,
                                               const float* __restrict__ val,
                                               float* __restrict__ partial) {
    __shared__ float tab[RSV];
    const int c = blockIdx.x, r = blockIdx.y;
    for (int j = threadIdx.x; j < RSV; j += 1024) tab[j] = 0.f;
    __syncthreads();
    const int base = r * RSV;
    const int i0 = c * PERV;
    // 2 int4-pairs per iteration; gathers hoisted (dst is always a valid node
    // id — the predicate is on the SRC range) so 8 loads issue independently.
    for (int i = i0 + (int)threadIdx.x * 2; i < i0 + PERV; i += 2048) {
        int4 s0 = src4[i];
        int4 s1 = src4[i + 1];
        int4 d0 = dst4[i];
        int4 d1 = dst4[i + 1];
        float v0 = val[d0.x], v1 = val[d0.y], v2 = val[d0.z], v3 = val[d0.w];
        float v4 = val[d1.x], v5 = val[d1.y], v6 = val[d1.z], v7 = val[d1.w];
        unsigned a;
        a = (unsigned)(s0.x - base); if (a < RSV) atomicAdd(&tab[a], v0);
        a = (unsigned)(s0.y - base); if (a < RSV) atomicAdd(&tab[a], v1);
        a = (unsigned)(s0.z - base); if (a < RSV) atomicAdd(&tab[a], v2);
        a = (unsigned)(s0.w - base); if (a < RSV) atomicAdd(&tab[a], v3);
        a = (unsigned)(s1.x - base); if (a < RSV) atomicAdd(&tab[a], v4);
        a = (unsigned)(s1.y - base); if (a < RSV) atomicAdd(&tab[a], v5);
        a = (unsigned)(s1.z - base); if (a < RSV) atomicAdd(&tab[a], v6);
        a = (unsigned)(s1.w - base); if (a < RSV) atomicAdd(&tab[a], v7);
    }
    __syncthreads();
    float* outp = partial + (size_t)(r * NCV + c) * RSV;
    for (int j = threadIdx.x; j < RSV; j += 1024) outp[j] = tab[j];
}

__global__ __launch_bounds__(256) void k_mws(const float* __restrict__ partial,
                                             const float* __restrict__ invc,
                                             float* __restrict__ ws, float* __restrict__ u) {
    int i = blockIdx.x * 256 + threadIdx.x;
    if (i >= NN) return;
    int rr = i / RSV, jj = i - rr * RSV;
    const float* p = partial + (size_t)rr * NCV * RSV + jj;
    float w = 0.f;
    #pragma unroll
    for (int c = 0; c < NCV; ++c) w += p[(size_t)c * RSV];
    ws[i] = w;
    u[i] = w * invc[i];
}

// ======================= fused merge_t + featsums stage-1 =======================

__global__ __launch_bounds__(1024) void k_fsm(const float* __restrict__ x,
                                              const float* __restrict__ ws,
                                              const float* __restrict__ partial,
                                              float* __restrict__ p1) {
    __shared__ float t_sl[SLICE], ws_sl[SLICE];
    __shared__ float shx[32][32][4], shw[32][32][4], sht[32][32][4], wsh[32];
    const int bid = blockIdx.x, tid = threadIdx.x;
    const int i0 = bid * SLICE;
    const int rr = bid / (RSV / SLICE);          // slice fully inside range rr
    const int jj0 = i0 - rr * RSV;

    if (tid < SLICE) {
        const float* p = partial + (size_t)rr * NCV * RSV + (jj0 + tid);
        float tv = 0.f;
        #pragma unroll
        for (int c = 0; c < NCV; ++c) tv += p[(size_t)c * RSV];
        t_sl[tid] = tv;
        ws_sl[tid] = ws[i0 + tid];
    }
    __syncthreads();

    const int lane = tid & 31;
    const int grp  = tid >> 5;                   // 0..31
    float sx0=0,sx1=0,sx2=0,sx3=0;
    float sw0=0,sw1=0,sw2=0,sw3=0;
    float st0=0,st1=0,st2=0,st3=0;
    float wsum = 0.f;
    for (int r = grp; r < SLICE; r += 32) {
        const float4* xr = (const float4*)(x + (size_t)(i0 + r) * FEAT);
        float4 v = xr[lane];
        float wr = ws_sl[r];
        float tr = t_sl[r];
        sx0 += v.x; sx1 += v.y; sx2 += v.z; sx3 += v.w;
        sw0 += wr*v.x; sw1 += wr*v.y; sw2 += wr*v.z; sw3 += wr*v.w;
        st0 += tr*v.x; st1 += tr*v.y; st2 += tr*v.z; st3 += tr*v.w;
        if (lane == 0) wsum += wr;
    }
    shx[grp][lane][0]=sx0; shx[grp][lane][1]=sx1; shx[grp][lane][2]=sx2; shx[grp][lane][3]=sx3;
    shw[grp][lane][0]=sw0; shw[grp][lane][1]=sw1; shw[grp][lane][2]=sw2; shw[grp][lane][3]=sw3;
    sht[grp][lane][0]=st0; sht[grp][lane][1]=st1; sht[grp][lane][2]=st2; sht[grp][lane][3]=st3;
    if (lane == 0) wsh[grp] = wsum;
    __syncthreads();

    if (grp == 0) {
        float ax[4]={0,0,0,0}, aw[4]={0,0,0,0}, at[4]={0,0,0,0};
        for (int g = 0; g < 32; ++g) {
            #pragma unroll
            for (int cc = 0; cc < 4; ++cc) {
                ax[cc] += shx[g][lane][cc];
                aw[cc] += shw[g][lane][cc];
                at[cc] += sht[g][lane][cc];
            }
        }
        // b-major: p1[bid*P1S + v] — contiguous 1.6 KB row per block
        float* row = p1 + (size_t)bid * P1S;
        #pragma unroll
        for (int cc = 0; cc < 4; ++cc) {
            row[        4*lane + cc] = ax[cc];
            row[FEAT  + 4*lane + cc] = aw[cc];
            row[2*FEAT+ 4*lane + cc] = at[cc];
        }
        if (lane == 0) {
            float w = 0.f;
            for (int g = 0; g < 32; ++g) w += wsh[g];
            row[3*FEAT] = w;
        }
    }
}

// ======================= fused reduce + matvecs =======================

__global__ __launch_bounds__(1024) void k_fin(const float* __restrict__ p1,
                                              const float* __restrict__ W1l, const float* __restrict__ W1r,
                                              const float* __restrict__ b1,
                                              const float* __restrict__ W2l, const float* __restrict__ W2r,
                                              const float* __restrict__ b2,
                                              const float* __restrict__ Wout, const float* __restrict__ bout,
                                              float* __restrict__ out) {
    __shared__ float part[NG][P1S];   // 10 x 400 floats = 16 KB
    __shared__ float fin[800];
    const int tid = threadIdx.x;

    if (tid < NG * NQ) {
        const int g = tid / NQ;        // 0..9
        const int q = tid - g * NQ;    // 0..99
        const float4* p4 = (const float4*)p1;
        float4 a0 = {0,0,0,0}, a1 = {0,0,0,0};
        const int b0 = g * (FSG / NG);
        #pragma unroll 5
        for (int b = b0; b < b0 + FSG / NG; b += 2) {
            float4 v0 = p4[(size_t)b * NQ + q];
            float4 v1 = p4[(size_t)(b + 1) * NQ + q];
            a0.x += v0.x; a0.y += v0.y; a0.z += v0.z; a0.w += v0.w;
            a1.x += v1.x; a1.y += v1.y; a1.z += v1.z; a1.w += v1.w;
        }
        part[g][4*q    ] = a0.x + a1.x;
        part[g][4*q + 1] = a0.y + a1.y;
        part[g][4*q + 2] = a0.z + a1.z;
        part[g][4*q + 3] = a0.w + a1.w;
    }
    __syncthreads();
    if (tid < NV) {
        float s = 0.f;
        #pragma unroll
        for (int g = 0; g < NG; ++g) s += part[g][tid];
        fin[tid] = s;      // [0..127]=Sx [128..255]=Sw [256..383]=St [384]=Wsum
    }
    __syncthreads();

    if (tid < FEAT) {
        float m1 = (float)NN * b1[tid];
        float s2 = fin[384] * b1[tid];
        for (int k = 0; k < FEAT; ++k) {
            float wl = W1l[k*FEAT + tid];
            float wr = W1r[k*FEAT + tid];
            m1 += fin[128 + k] * wl + fin[k] * wr;         // Sw@W1l + Sx@W1r
            s2 += fin[256 + k] * wl + fin[128 + k] * wr;   // St@W1l + Sw@W1r
        }
        fin[400 + tid] = m1;
        fin[528 + tid] = s2;
    }
    __syncthreads();
    if (tid < FEAT) {
        float g = 0.f;
        for (int k = 0; k < FEAT; ++k)
            g += fin[528 + k] * W2l[k*FEAT + tid] + fin[400 + k] * W2r[k*FEAT + tid];
        fin[656 + tid] = g * (1.0f / (float)NN) + b2[tid];
    }
    __syncthreads();
    if (tid < NCLS) {
        float o = bout[tid];
        for (int k = 0; k < FEAT; ++k)
            o += fin[656 + k] * Wout[k*NCLS + tid];
        out[tid] = o;
    }
}

// ======================= device-scope fallback (tiny ws_size) =======================

__global__ __launch_bounds__(256) void k_count_dev(const int4* __restrict__ dst4, int* __restrict__ cnt) {
    int i = blockIdx.x * 256 + threadIdx.x;
    if (i >= NE4) return;
    int4 d = dst4[i];
    atomicAdd(&cnt[d.x], 1); atomicAdd(&cnt[d.y], 1);
    atomicAdd(&cnt[d.z], 1); atomicAdd(&cnt[d.w], 1);
}

__global__ __launch_bounds__(256) void k_inv_dev(const int* __restrict__ cnt, float* __restrict__ invc) {
    int i = blockIdx.x * 256 + threadIdx.x;
    if (i >= NN) return;
    int c = cnt[i];
    invc[i] = 1.0f / (float)(c > 0 ? c : 1);
}

__global__ __launch_bounds__(256) void k_ws_dev(const int4* __restrict__ src4, const int4* __restrict__ dst4,
                                                const float* __restrict__ invc, float* __restrict__ ws) {
    int i = blockIdx.x * 256 + threadIdx.x;
    if (i >= NE4) return;
    int4 s = src4[i];
    int4 d = dst4[i];
    atomicAdd(&ws[s.x], invc[d.x]); atomicAdd(&ws[s.y], invc[d.y]);
    atomicAdd(&ws[s.z], invc[d.z]); atomicAdd(&ws[s.w], invc[d.w]);
}

__global__ __launch_bounds__(256) void k_u_dev(const float* __restrict__ ws, const float* __restrict__ invc,
                                               float* __restrict__ u) {
    int i = blockIdx.x * 256 + threadIdx.x;
    if (i >= NN) return;
    u[i] = ws[i] * invc[i];
}

__global__ __launch_bounds__(256) void k_t_dev(const int4* __restrict__ src4, const int4* __restrict__ dst4,
                                               const float* __restrict__ u, float* __restrict__ t) {
    int i = blockIdx.x * 256 + threadIdx.x;
    if (i >= NE4) return;
    int4 s = src4[i];
    int4 d = dst4[i];
    atomicAdd(&t[s.x], u[d.x]); atomicAdd(&t[s.y], u[d.y]);
    atomicAdd(&t[s.z], u[d.z]); atomicAdd(&t[s.w], u[d.w]);
}

__global__ __launch_bounds__(256) void k_fs_atom(const float* __restrict__ x,
                                                 const float* __restrict__ ws,
                                                 const float* __restrict__ t,
                                                 float* __restrict__ sums) {
    int lane = threadIdx.x & 31;
    int grp  = threadIdx.x >> 5;
    int row0 = blockIdx.x * 8 + grp;
    int rstride = gridDim.x * 8;
    float sx0=0,sx1=0,sx2=0,sx3=0, sw0=0,sw1=0,sw2=0,sw3=0, st0=0,st1=0,st2=0,st3=0, wsum=0.f;
    for (int r = row0; r < NN; r += rstride) {
        const float4* xr = (const float4*)(x + (size_t)r * FEAT);
        float4 v = xr[lane];
        float wr = ws[r], tr = t[r];
        sx0+=v.x; sx1+=v.y; sx2+=v.z; sx3+=v.w;
        sw0+=wr*v.x; sw1+=wr*v.y; sw2+=wr*v.z; sw3+=wr*v.w;
        st0+=tr*v.x; st1+=tr*v.y; st2+=tr*v.z; st3+=tr*v.w;
        if (lane==0) wsum += wr;
    }
    __shared__ float shx[8][32][4], shw[8][32][4], sht[8][32][4], shwsum[8];
    shx[grp][lane][0]=sx0; shx[grp][lane][1]=sx1; shx[grp][lane][2]=sx2; shx[grp][lane][3]=sx3;
    shw[grp][lane][0]=sw0; shw[grp][lane][1]=sw1; shw[grp][lane][2]=sw2; shw[grp][lane][3]=sw3;
    sht[grp][lane][0]=st0; sht[grp][lane][1]=st1; sht[grp][lane][2]=st2; sht[grp][lane][3]=st3;
    if (lane==0) shwsum[grp]=wsum;
    __syncthreads();
    if (grp==0) {
        float ax[4], aw[4], at[4];
        #pragma unroll
        for (int c=0;c<4;++c){ax[c]=shx[0][lane][c];aw[c]=shw[0][lane][c];at[c]=sht[0][lane][c];}
        #pragma unroll
        for (int g=1;g<8;++g)
            #pragma unroll
            for (int c=0;c<4;++c){ax[c]+=shx[g][lane][c];aw[c]+=shw[g][lane][c];at[c]+=sht[g][lane][c];}
        #pragma unroll
        for (int c=0;c<4;++c){
            atomicAdd(&sums[        4*lane+c], ax[c]);
            atomicAdd(&sums[FEAT  + 4*lane+c], aw[c]);
            atomicAdd(&sums[2*FEAT+ 4*lane+c], at[c]);
        }
        if (lane==0){
            float w=shwsum[0];
            #pragma unroll
            for (int g=1;g<8;++g) w+=shwsum[g];
            atomicAdd(&sums[3*FEAT], w);
        }
    }
}

__global__ __launch_bounds__(128) void k_final_dev(const float* __restrict__ sums,
                                                   const float* __restrict__ W1l, const float* __restrict__ W1r,
                                                   const float* __restrict__ b1,
                                                   const float* __restrict__ W2l, const float* __restrict__ W2r,
                                                   const float* __restrict__ b2,
                                                   const float* __restrict__ Wout, const float* __restrict__ bout,
                                                   float* __restrict__ out) {
    __shared__ float Sx[FEAT], Sw[FEAT], St[FEAT], M1[FEAT], S2[FEAT], G[FEAT];
    __shared__ float Wsum;
    int f = threadIdx.x;
    Sx[f] = sums[f];
    Sw[f] = sums[FEAT + f];
    St[f] = sums[2*FEAT + f];
    if (f == 0) Wsum = sums[3*FEAT];
    __syncthreads();
    float m1 = (float)NN * b1[f];
    float s2 = Wsum * b1[f];
    for (int k = 0; k < FEAT; ++k) {
        float wl = W1l[k*FEAT + f];
        float wr = W1r[k*FEAT + f];
        m1 += Sw[k]*wl + Sx[k]*wr;
        s2 += St[k]*wl + Sw[k]*wr;
    }
    M1[f] = m1; S2[f] = s2;
    __syncthreads();
    float g = 0.f;
    for (int k = 0; k < FEAT; ++k)
        g += S2[k]*W2l[k*FEAT + f] + M1[k]*W2r[k*FEAT + f];
    g = g * (1.0f/(float)NN) + b2[f];
    G[f] = g;
    __syncthreads();
    if (f < NCLS) {
        float o = bout[f];
        for (int k = 0; k < FEAT; ++k)
            o += G[k]*Wout[k*NCLS + f];
        out[f] = o;
    }
}

// ======================= driver =======================

extern "C" void kernel_launch(void* const* d_in, const int* in_sizes, int n_in,
                              void* d_out, int out_size, void* d_ws, size_t ws_size,
                              hipStream_t stream) {
    const float* x    = (const float*)d_in[0];
    const int*   ei   = (const int*)d_in[1];     // [2, NE] flat: src then dst (int32 on device)
    const float* W1l  = (const float*)d_in[2];
    const float* W1r  = (const float*)d_in[3];
    const float* b1   = (const float*)d_in[4];
    const float* W2l  = (const float*)d_in[5];
    const float* W2r  = (const float*)d_in[6];
    const float* b2   = (const float*)d_in[7];
    const float* Wout = (const float*)d_in[8];
    const float* bout = (const float*)d_in[9];
    float* out = (float*)d_out;

    const int4* src4 = (const int4*)ei;
    const int4* dst4 = (const int4*)(ei + NE);

    const size_t PART = (size_t)NRV * NCV * RSV;                 // 3,584,000 floats
    const size_t P1N  = (size_t)FSG * P1S;                       // 200,000 floats
    const size_t need = (PART + (size_t)3*NN + P1N) * 4;         // ~16.3 MB

    if (ws_size >= need) {
        float* partial = (float*)d_ws;                 // also holds count partials (6.4 MB)
        float* invc = partial + PART;
        float* ws   = invc + NN;
        float* u    = ws + NN;
        float* p1   = u + NN;

        const int NB = (NN + 255) / 256;

        k_cnt8<<<dim3(NCC, NRC), 1024, 0, stream>>>(dst4, (unsigned*)partial);
        k_inv<<<NB, 256, 0, stream>>>((const unsigned*)partial, invc);
        k_scat<<<dim3(NCV, NRV), 1024, 0, stream>>>(src4, dst4, invc, partial);
        k_mws<<<NB, 256, 0, stream>>>(partial, invc, ws, u);
        k_scat<<<dim3(NCV, NRV), 1024, 0, stream>>>(src4, dst4, u, partial);
        k_fsm<<<FSG, 1024, 0, stream>>>(x, ws, partial, p1);
        k_fin<<<1, 1024, 0, stream>>>(p1, W1l, W1r, b1, W2l, W2r, b2, Wout, bout, out);
    } else {
        // device-scope atomic fallback (~2.1 MB ws)
        int*   cnt  = (int*)d_ws;
        float* wsv  = (float*)d_ws + NN;
        float* t    = (float*)d_ws + 2*NN;
        float* sums = (float*)d_ws + 3*NN;
        float* invc = (float*)d_ws + 3*NN + 640;
        float* u    = (float*)d_ws + 3*NN + 640 + NN;

        hipMemsetAsync(d_ws, 0, ((size_t)3*NN + 640) * 4, stream);

        const int EB4 = (NE4 + 255) / 256;
        const int NB  = (NN + 255) / 256;
        k_count_dev<<<EB4, 256, 0, stream>>>(dst4, cnt);
        k_inv_dev<<<NB, 256, 0, stream>>>(cnt, invc);
        k_ws_dev<<<EB4, 256, 0, stream>>>(src4, dst4, invc, wsv);
        k_u_dev<<<NB, 256, 0, stream>>>(wsv, invc, u);
        k_t_dev<<<EB4, 256, 0, stream>>>(src4, dst4, u, t);
        k_fs_atom<<<256, 256, 0, stream>>>(x, wsv, t, sums);
        k_final_dev<<<1, 128, 0, stream>>>(sums, W1l, W1r, b1, W2l, W2r, b2, Wout, bout, out);
    }
}

// Round 14
// 186.111 us; speedup vs baseline: 1.3012x; 1.3012x over previous
//
#include <hip/hip_runtime.h>

// GraphSAGE (2x SAGEConv mean + global_mean_pool + linear) collapsed algebraically:
// out = (((St@W1l + Sw@W1r + Wsum*b1) @ W2l + (Sw@W1l + Sx@W1r + N*b1) @ W2r)/N + b2) @ Wout + bout
// invc_i = 1/max(indeg_i,1), ws_j = sum_{e:src=j} invc[dst_e], u_j = ws_j*invc_j,
// t_k = sum_{e:src=k} u[dst_e]; Sx/Sw/St = weighted column sums of x; Wsum = sum ws.
//
// R13: exact revert to R11 (best: 187 us). R12's hoisted gathers multiplied
// gather requests x7 (52 us/scat, L2 request-rate bound) — gathers must stay
// predicated on the src-range test. R13 counters also proved the NRV=7
// redundant edge scans are L2-absorbed (scat FETCH 7.8 MB << 90 MB scanned).
// Invariants: no global atomics (memory-side regardless of scope: R2/R4),
// no grid.sync (~30 us/barrier: R7), LDS range privatization, 7 dispatches,
// single-block reduces need short dep chains + coalesced float4 (R10/R11).

#define NN    100000
#define NE    1600000
#define NE4   (NE/4)
#define FEAT  128
#define NCLS  40

// count pass (u8-packed)
#define RSC   25000    // nodes per range; 4 cnt/u32 -> 25,000 B LDS
#define NRC   4        // 4*25000 = 100000 exactly
#define NCC   64
#define PERC  6250     // int4 per chunk (64*6250 = 400000)

// scatter passes
#define RSV   16000    // 64,000 B LDS
#define NRV   7
#define NCV   32
#define PERV  12500

// fused merge_t + featsums
#define SLICE 200
#define FSG   500      // grid; 500*200 = 100000 exactly
#define P1S   400      // p1 row stride floats, b-major: p1[b*P1S + v]
#define NV    (3*FEAT + 1)   // 385
#define NQ    (P1S / 4)      // 100 float4 columns per row
#define NG    10             // b-groups in k_fin reduce (10*50 = FSG)

// ======================= count: u8-packed LDS histogram =======================

__global__ __launch_bounds__(1024) void k_cnt8(const int4* __restrict__ dst4,
                                               unsigned* __restrict__ pc) {
    __shared__ unsigned tab[RSC / 4];
    const int c = blockIdx.x, r = blockIdx.y;
    for (int j = threadIdx.x; j < RSC / 4; j += 1024) tab[j] = 0u;
    __syncthreads();
    const int base = r * RSC;
    const int i0 = c * PERC;
    for (int i = i0 + (int)threadIdx.x; i < i0 + PERC; i += 1024) {
        int4 d = dst4[i];
        unsigned a;
        a = (unsigned)(d.x - base); if (a < RSC) atomicAdd(&tab[a >> 2], 1u << ((a & 3) * 8));
        a = (unsigned)(d.y - base); if (a < RSC) atomicAdd(&tab[a >> 2], 1u << ((a & 3) * 8));
        a = (unsigned)(d.z - base); if (a < RSC) atomicAdd(&tab[a >> 2], 1u << ((a & 3) * 8));
        a = (unsigned)(d.w - base); if (a < RSC) atomicAdd(&tab[a >> 2], 1u << ((a & 3) * 8));
    }
    __syncthreads();
    unsigned* outp = pc + (size_t)(r * NCC + c) * (RSC / 4);
    for (int j = threadIdx.x; j < RSC / 4; j += 1024) outp[j] = tab[j];
}

__global__ __launch_bounds__(256) void k_inv(const unsigned* __restrict__ pc,
                                             float* __restrict__ invc) {
    int i = blockIdx.x * 256 + threadIdx.x;
    if (i >= NN) return;
    int rr = i / RSC, jj = i - rr * RSC;
    const unsigned* p = pc + (size_t)rr * NCC * (RSC / 4) + (jj >> 2);
    const unsigned sh = (unsigned)(jj & 3) * 8u;
    unsigned cn = 0;
    #pragma unroll 16
    for (int c = 0; c < NCC; ++c) cn += (p[(size_t)c * (RSC / 4)] >> sh) & 0xFFu;
    invc[i] = 1.0f / (float)(cn > 0u ? cn : 1u);
}

// ======================= scatter: 64 KB LDS tables =======================

__global__ __launch_bounds__(1024) void k_scat(const int4* __restrict__ src4,
                                               const int4* __restrict__ dst4,
                                               const float* __restrict__ val,
                                               float* __restrict__ partial) {
    __shared__ float tab[RSV];
    const int c = blockIdx.x, r = blockIdx.y;
    for (int j = threadIdx.x; j < RSV; j += 1024) tab[j] = 0.f;
    __syncthreads();
    const int base = r * RSV;
    const int i0 = c * PERV;
    for (int i = i0 + (int)threadIdx.x; i < i0 + PERV; i += 1024) {
        int4 s = src4[i];
        int4 d = dst4[i];
        unsigned a;
        a = (unsigned)(s.x - base); if (a < RSV) atomicAdd(&tab[a], val[d.x]);
        a = (unsigned)(s.y - base); if (a < RSV) atomicAdd(&tab[a], val[d.y]);
        a = (unsigned)(s.z - base); if (a < RSV) atomicAdd(&tab[a], val[d.z]);
        a = (unsigned)(s.w - base); if (a < RSV) atomicAdd(&tab[a], val[d.w]);
    }
    __syncthreads();
    float* outp = partial + (size_t)(r * NCV + c) * RSV;
    for (int j = threadIdx.x; j < RSV; j += 1024) outp[j] = tab[j];
}

__global__ __launch_bounds__(256) void k_mws(const float* __restrict__ partial,
                                             const float* __restrict__ invc,
                                             float* __restrict__ ws, float* __restrict__ u) {
    int i = blockIdx.x * 256 + threadIdx.x;
    if (i >= NN) return;
    int rr = i / RSV, jj = i - rr * RSV;
    const float* p = partial + (size_t)rr * NCV * RSV + jj;
    float w = 0.f;
    #pragma unroll
    for (int c = 0; c < NCV; ++c) w += p[(size_t)c * RSV];
    ws[i] = w;
    u[i] = w * invc[i];
}

// ======================= fused merge_t + featsums stage-1 =======================

__global__ __launch_bounds__(1024) void k_fsm(const float* __restrict__ x,
                                              const float* __restrict__ ws,
                                              const float* __restrict__ partial,
                                              float* __restrict__ p1) {
    __shared__ float t_sl[SLICE], ws_sl[SLICE];
    __shared__ float shx[32][32][4], shw[32][32][4], sht[32][32][4], wsh[32];
    const int bid = blockIdx.x, tid = threadIdx.x;
    const int i0 = bid * SLICE;
    const int rr = bid / (RSV / SLICE);          // slice fully inside range rr
    const int jj0 = i0 - rr * RSV;

    if (tid < SLICE) {
        const float* p = partial + (size_t)rr * NCV * RSV + (jj0 + tid);
        float tv = 0.f;
        #pragma unroll
        for (int c = 0; c < NCV; ++c) tv += p[(size_t)c * RSV];
        t_sl[tid] = tv;
        ws_sl[tid] = ws[i0 + tid];
    }
    __syncthreads();

    const int lane = tid & 31;
    const int grp  = tid >> 5;                   // 0..31
    float sx0=0,sx1=0,sx2=0,sx3=0;
    float sw0=0,sw1=0,sw2=0,sw3=0;
    float st0=0,st1=0,st2=0,st3=0;
    float wsum = 0.f;
    for (int r = grp; r < SLICE; r += 32) {
        const float4* xr = (const float4*)(x + (size_t)(i0 + r) * FEAT);
        float4 v = xr[lane];
        float wr = ws_sl[r];
        float tr = t_sl[r];
        sx0 += v.x; sx1 += v.y; sx2 += v.z; sx3 += v.w;
        sw0 += wr*v.x; sw1 += wr*v.y; sw2 += wr*v.z; sw3 += wr*v.w;
        st0 += tr*v.x; st1 += tr*v.y; st2 += tr*v.z; st3 += tr*v.w;
        if (lane == 0) wsum += wr;
    }
    shx[grp][lane][0]=sx0; shx[grp][lane][1]=sx1; shx[grp][lane][2]=sx2; shx[grp][lane][3]=sx3;
    shw[grp][lane][0]=sw0; shw[grp][lane][1]=sw1; shw[grp][lane][2]=sw2; shw[grp][lane][3]=sw3;
    sht[grp][lane][0]=st0; sht[grp][lane][1]=st1; sht[grp][lane][2]=st2; sht[grp][lane][3]=st3;
    if (lane == 0) wsh[grp] = wsum;
    __syncthreads();

    if (grp == 0) {
        float ax[4]={0,0,0,0}, aw[4]={0,0,0,0}, at[4]={0,0,0,0};
        for (int g = 0; g < 32; ++g) {
            #pragma unroll
            for (int cc = 0; cc < 4; ++cc) {
                ax[cc] += shx[g][lane][cc];
                aw[cc] += shw[g][lane][cc];
                at[cc] += sht[g][lane][cc];
            }
        }
        // b-major: p1[bid*P1S + v] — contiguous 1.6 KB row per block
        float* row = p1 + (size_t)bid * P1S;
        #pragma unroll
        for (int cc = 0; cc < 4; ++cc) {
            row[        4*lane + cc] = ax[cc];
            row[FEAT  + 4*lane + cc] = aw[cc];
            row[2*FEAT+ 4*lane + cc] = at[cc];
        }
        if (lane == 0) {
            float w = 0.f;
            for (int g = 0; g < 32; ++g) w += wsh[g];
            row[3*FEAT] = w;
        }
    }
}

// ======================= fused reduce + matvecs =======================

__global__ __launch_bounds__(1024) void k_fin(const float* __restrict__ p1,
                                              const float* __restrict__ W1l, const float* __restrict__ W1r,
                                              const float* __restrict__ b1,
                                              const float* __restrict__ W2l, const float* __restrict__ W2r,
                                              const float* __restrict__ b2,
                                              const float* __restrict__ Wout, const float* __restrict__ bout,
                                              float* __restrict__ out) {
    __shared__ float part[NG][P1S];   // 10 x 400 floats = 16 KB
    __shared__ float fin[800];
    const int tid = threadIdx.x;

    if (tid < NG * NQ) {
        const int g = tid / NQ;        // 0..9
        const int q = tid - g * NQ;    // 0..99
        const float4* p4 = (const float4*)p1;
        float4 a0 = {0,0,0,0}, a1 = {0,0,0,0};
        const int b0 = g * (FSG / NG);
        #pragma unroll 5
        for (int b = b0; b < b0 + FSG / NG; b += 2) {
            float4 v0 = p4[(size_t)b * NQ + q];
            float4 v1 = p4[(size_t)(b + 1) * NQ + q];
            a0.x += v0.x; a0.y += v0.y; a0.z += v0.z; a0.w += v0.w;
            a1.x += v1.x; a1.y += v1.y; a1.z += v1.z; a1.w += v1.w;
        }
        part[g][4*q    ] = a0.x + a1.x;
        part[g][4*q + 1] = a0.y + a1.y;
        part[g][4*q + 2] = a0.z + a1.z;
        part[g][4*q + 3] = a0.w + a1.w;
    }
    __syncthreads();
    if (tid < NV) {
        float s = 0.f;
        #pragma unroll
        for (int g = 0; g < NG; ++g) s += part[g][tid];
        fin[tid] = s;      // [0..127]=Sx [128..255]=Sw [256..383]=St [384]=Wsum
    }
    __syncthreads();

    if (tid < FEAT) {
        float m1 = (float)NN * b1[tid];
        float s2 = fin[384] * b1[tid];
        for (int k = 0; k < FEAT; ++k) {
            float wl = W1l[k*FEAT + tid];
            float wr = W1r[k*FEAT + tid];
            m1 += fin[128 + k] * wl + fin[k] * wr;         // Sw@W1l + Sx@W1r
            s2 += fin[256 + k] * wl + fin[128 + k] * wr;   // St@W1l + Sw@W1r
        }
        fin[400 + tid] = m1;
        fin[528 + tid] = s2;
    }
    __syncthreads();
    if (tid < FEAT) {
        float g = 0.f;
        for (int k = 0; k < FEAT; ++k)
            g += fin[528 + k] * W2l[k*FEAT + tid] + fin[400 + k] * W2r[k*FEAT + tid];
        fin[656 + tid] = g * (1.0f / (float)NN) + b2[tid];
    }
    __syncthreads();
    if (tid < NCLS) {
        float o = bout[tid];
        for (int k = 0; k < FEAT; ++k)
            o += fin[656 + k] * Wout[k*NCLS + tid];
        out[tid] = o;
    }
}

// ======================= device-scope fallback (tiny ws_size) =======================

__global__ __launch_bounds__(256) void k_count_dev(const int4* __restrict__ dst4, int* __restrict__ cnt) {
    int i = blockIdx.x * 256 + threadIdx.x;
    if (i >= NE4) return;
    int4 d = dst4[i];
    atomicAdd(&cnt[d.x], 1); atomicAdd(&cnt[d.y], 1);
    atomicAdd(&cnt[d.z], 1); atomicAdd(&cnt[d.w], 1);
}

__global__ __launch_bounds__(256) void k_inv_dev(const int* __restrict__ cnt, float* __restrict__ invc) {
    int i = blockIdx.x * 256 + threadIdx.x;
    if (i >= NN) return;
    int c = cnt[i];
    invc[i] = 1.0f / (float)(c > 0 ? c : 1);
}

__global__ __launch_bounds__(256) void k_ws_dev(const int4* __restrict__ src4, const int4* __restrict__ dst4,
                                                const float* __restrict__ invc, float* __restrict__ ws) {
    int i = blockIdx.x * 256 + threadIdx.x;
    if (i >= NE4) return;
    int4 s = src4[i];
    int4 d = dst4[i];
    atomicAdd(&ws[s.x], invc[d.x]); atomicAdd(&ws[s.y], invc[d.y]);
    atomicAdd(&ws[s.z], invc[d.z]); atomicAdd(&ws[s.w], invc[d.w]);
}

__global__ __launch_bounds__(256) void k_u_dev(const float* __restrict__ ws, const float* __restrict__ invc,
                                               float* __restrict__ u) {
    int i = blockIdx.x * 256 + threadIdx.x;
    if (i >= NN) return;
    u[i] = ws[i] * invc[i];
}

__global__ __launch_bounds__(256) void k_t_dev(const int4* __restrict__ src4, const int4* __restrict__ dst4,
                                               const float* __restrict__ u, float* __restrict__ t) {
    int i = blockIdx.x * 256 + threadIdx.x;
    if (i >= NE4) return;
    int4 s = src4[i];
    int4 d = dst4[i];
    atomicAdd(&t[s.x], u[d.x]); atomicAdd(&t[s.y], u[d.y]);
    atomicAdd(&t[s.z], u[d.z]); atomicAdd(&t[s.w], u[d.w]);
}

__global__ __launch_bounds__(256) void k_fs_atom(const float* __restrict__ x,
                                                 const float* __restrict__ ws,
                                                 const float* __restrict__ t,
                                                 float* __restrict__ sums) {
    int lane = threadIdx.x & 31;
    int grp  = threadIdx.x >> 5;
    int row0 = blockIdx.x * 8 + grp;
    int rstride = gridDim.x * 8;
    float sx0=0,sx1=0,sx2=0,sx3=0, sw0=0,sw1=0,sw2=0,sw3=0, st0=0,st1=0,st2=0,st3=0, wsum=0.f;
    for (int r = row0; r < NN; r += rstride) {
        const float4* xr = (const float4*)(x + (size_t)r * FEAT);
        float4 v = xr[lane];
        float wr = ws[r], tr = t[r];
        sx0+=v.x; sx1+=v.y; sx2+=v.z; sx3+=v.w;
        sw0+=wr*v.x; sw1+=wr*v.y; sw2+=wr*v.z; sw3+=wr*v.w;
        st0+=tr*v.x; st1+=tr*v.y; st2+=tr*v.z; st3+=tr*v.w;
        if (lane==0) wsum += wr;
    }
    __shared__ float shx[8][32][4], shw[8][32][4], sht[8][32][4], shwsum[8];
    shx[grp][lane][0]=sx0; shx[grp][lane][1]=sx1; shx[grp][lane][2]=sx2; shx[grp][lane][3]=sx3;
    shw[grp][lane][0]=sw0; shw[grp][lane][1]=sw1; shw[grp][lane][2]=sw2; shw[grp][lane][3]=sw3;
    sht[grp][lane][0]=st0; sht[grp][lane][1]=st1; sht[grp][lane][2]=st2; sht[grp][lane][3]=st3;
    if (lane==0) shwsum[grp]=wsum;
    __syncthreads();
    if (grp==0) {
        float ax[4], aw[4], at[4];
        #pragma unroll
        for (int c=0;c<4;++c){ax[c]=shx[0][lane][c];aw[c]=shw[0][lane][c];at[c]=sht[0][lane][c];}
        #pragma unroll
        for (int g=1;g<8;++g)
            #pragma unroll
            for (int c=0;c<4;++c){ax[c]+=shx[g][lane][c];aw[c]+=shw[g][lane][c];at[c]+=sht[g][lane][c];}
        #pragma unroll
        for (int c=0;c<4;++c){
            atomicAdd(&sums[        4*lane+c], ax[c]);
            atomicAdd(&sums[FEAT  + 4*lane+c], aw[c]);
            atomicAdd(&sums[2*FEAT+ 4*lane+c], at[c]);
        }
        if (lane==0){
            float w=shwsum[0];
            #pragma unroll
            for (int g=1;g<8;++g) w+=shwsum[g];
            atomicAdd(&sums[3*FEAT], w);
        }
    }
}

__global__ __launch_bounds__(128) void k_final_dev(const float* __restrict__ sums,
                                                   const float* __restrict__ W1l, const float* __restrict__ W1r,
                                                   const float* __restrict__ b1,
                                                   const float* __restrict__ W2l, const float* __restrict__ W2r,
                                                   const float* __restrict__ b2,
                                                   const float* __restrict__ Wout, const float* __restrict__ bout,
                                                   float* __restrict__ out) {
    __shared__ float Sx[FEAT], Sw[FEAT], St[FEAT], M1[FEAT], S2[FEAT], G[FEAT];
    __shared__ float Wsum;
    int f = threadIdx.x;
    Sx[f] = sums[f];
    Sw[f] = sums[FEAT + f];
    St[f] = sums[2*FEAT + f];
    if (f == 0) Wsum = sums[3*FEAT];
    __syncthreads();
    float m1 = (float)NN * b1[f];
    float s2 = Wsum * b1[f];
    for (int k = 0; k < FEAT; ++k) {
        float wl = W1l[k*FEAT + f];
        float wr = W1r[k*FEAT + f];
        m1 += Sw[k]*wl + Sx[k]*wr;
        s2 += St[k]*wl + Sw[k]*wr;
    }
    M1[f] = m1; S2[f] = s2;
    __syncthreads();
    float g = 0.f;
    for (int k = 0; k < FEAT; ++k)
        g += S2[k]*W2l[k*FEAT + f] + M1[k]*W2r[k*FEAT + f];
    g = g * (1.0f/(float)NN) + b2[f];
    G[f] = g;
    __syncthreads();
    if (f < NCLS) {
        float o = bout[f];
        for (int k = 0; k < FEAT; ++k)
            o += G[k]*Wout[k*NCLS + f];
        out[f] = o;
    }
}

// ======================= driver =======================

extern "C" void kernel_launch(void* const* d_in, const int* in_sizes, int n_in,
                              void* d_out, int out_size, void* d_ws, size_t ws_size,
                              hipStream_t stream) {
    const float* x    = (const float*)d_in[0];
    const int*   ei   = (const int*)d_in[1];     // [2, NE] flat: src then dst (int32 on device)
    const float* W1l  = (const float*)d_in[2];
    const float* W1r  = (const float*)d_in[3];
    const float* b1   = (const float*)d_in[4];
    const float* W2l  = (const float*)d_in[5];
    const float* W2r  = (const float*)d_in[6];
    const float* b2   = (const float*)d_in[7];
    const float* Wout = (const float*)d_in[8];
    const float* bout = (const float*)d_in[9];
    float* out = (float*)d_out;

    const int4* src4 = (const int4*)ei;
    const int4* dst4 = (const int4*)(ei + NE);

    const size_t PART = (size_t)NRV * NCV * RSV;                 // 3,584,000 floats
    const size_t P1N  = (size_t)FSG * P1S;                       // 200,000 floats
    const size_t need = (PART + (size_t)3*NN + P1N) * 4;         // ~16.3 MB

    if (ws_size >= need) {
        float* partial = (float*)d_ws;                 // also holds count partials (6.4 MB)
        float* invc = partial + PART;
        float* ws   = invc + NN;
        float* u    = ws + NN;
        float* p1   = u + NN;

        const int NB = (NN + 255) / 256;

        k_cnt8<<<dim3(NCC, NRC), 1024, 0, stream>>>(dst4, (unsigned*)partial);
        k_inv<<<NB, 256, 0, stream>>>((const unsigned*)partial, invc);
        k_scat<<<dim3(NCV, NRV), 1024, 0, stream>>>(src4, dst4, invc, partial);
        k_mws<<<NB, 256, 0, stream>>>(partial, invc, ws, u);
        k_scat<<<dim3(NCV, NRV), 1024, 0, stream>>>(src4, dst4, u, partial);
        k_fsm<<<FSG, 1024, 0, stream>>>(x, ws, partial, p1);
        k_fin<<<1, 1024, 0, stream>>>(p1, W1l, W1r, b1, W2l, W2r, b2, Wout, bout, out);
    } else {
        // device-scope atomic fallback (~2.1 MB ws)
        int*   cnt  = (int*)d_ws;
        float* wsv  = (float*)d_ws + NN;
        float* t    = (float*)d_ws + 2*NN;
        float* sums = (float*)d_ws + 3*NN;
        float* invc = (float*)d_ws + 3*NN + 640;
        float* u    = (float*)d_ws + 3*NN + 640 + NN;

        hipMemsetAsync(d_ws, 0, ((size_t)3*NN + 640) * 4, stream);

        const int EB4 = (NE4 + 255) / 256;
        const int NB  = (NN + 255) / 256;
        k_count_dev<<<EB4, 256, 0, stream>>>(dst4, cnt);
        k_inv_dev<<<NB, 256, 0, stream>>>(cnt, invc);
        k_ws_dev<<<EB4, 256, 0, stream>>>(src4, dst4, invc, wsv);
        k_u_dev<<<NB, 256, 0, stream>>>(wsv, invc, u);
        k_t_dev<<<EB4, 256, 0, stream>>>(src4, dst4, u, t);
        k_fs_atom<<<256, 256, 0, stream>>>(x, wsv, t, sums);
        k_final_dev<<<1, 128, 0, stream>>>(sums, W1l, W1r, b1, W2l, W2r, b2, Wout, bout, out);
    }
}